// Round 4
// baseline (946.142 us; speedup 1.0000x reference)
//
#include <hip/hip_runtime.h>
#include <hip/hip_bf16.h>

// GCN: 3x (aggregate -> linear) with BN+ReLU between layers.
// R4: CSR build via two-level bucket sort (no random-scatter writebacks,
// no 1.6M-atomic histogram, row_ptr emitted by per-bucket counting sort).
// Agg kernels get 1-deep data prefetch. MFMA GEMM w/ split weights as R3.

using short8 = __attribute__((ext_vector_type(8))) short;
using f32x4  = __attribute__((ext_vector_type(4))) float;

__device__ __forceinline__ float bf_lo(unsigned int u) { return __uint_as_float(u << 16); }
__device__ __forceinline__ float bf_hi(unsigned int u) { return __uint_as_float(u & 0xffff0000u); }
__device__ __forceinline__ unsigned short f2bf(float f) {
    __hip_bfloat16 h = __float2bfloat16(f);
    return *reinterpret_cast<unsigned short*>(&h);
}
__device__ __forceinline__ int clampi(int v, int lo, int hi) {
    return v < lo ? lo : (v > hi ? hi : v);
}

#define BSH 7  // 128 nodes per bucket; NB = ceil(n/128) <= 1024 for n <= 131072

// ---------------- dtype detection ----------------
// flags[0]=1 if float tensors are bf16 else fp32; flags[1]=1 if edge_index int64

__global__ void detect_kernel(const unsigned int* __restrict__ gamma_raw,
                              const int* __restrict__ edge_raw, int* __restrict__ flags) {
    if (blockIdx.x == 0 && threadIdx.x == 0) {
        flags[0] = (gamma_raw[0] == 0x3F803F80u) ? 1 : 0;
        int is64 = 1;
        for (int i = 1; i <= 15; i += 2)
            if (edge_raw[i] != 0) is64 = 0;
        flags[1] = is64;
    }
}

// ---------------- param conversion ----------------

struct CvtPack {
    const void* src[10];
    void* dstA[10];
    void* dstB[10];
    int sz[10];
    int mode[10];
};

__global__ void cvt_params_kernel(CvtPack pp, const int* __restrict__ flags) {
    int b = blockIdx.x;
    int sz = pp.sz[b];
    int bf = flags[0];
    for (int i = threadIdx.x; i < sz; i += blockDim.x) {
        float w = bf ? __bfloat162float(((const __hip_bfloat16*)pp.src[b])[i])
                     : ((const float*)pp.src[b])[i];
        if (pp.mode[b] == 0) {
            ((float*)pp.dstA[b])[i] = w;
        } else {
            __hip_bfloat16 hi = __float2bfloat16(w);
            float r = w - __bfloat162float(hi);
            ((__hip_bfloat16*)pp.dstA[b])[i] = hi;
            ((__hip_bfloat16*)pp.dstB[b])[i] = __float2bfloat16(r);
        }
    }
}

// ---------------- CSR build: bucket sort ----------------

__global__ __launch_bounds__(256) void bucket_count_kernel(
    const int* __restrict__ edge, const int* __restrict__ flags,
    int* __restrict__ bucket_cnt, int E, int n, int NB) {
    __shared__ int hist[1024];
    for (int i = threadIdx.x; i < NB; i += 256) hist[i] = 0;
    __syncthreads();
    int base = blockIdx.x * 8192;
    int end = base + 8192 < E ? base + 8192 : E;
    int is64 = flags[1];
    for (int e = base + (int)threadIdx.x; e < end; e += 256) {
        int r = is64 ? edge[2 * e] : edge[e];
        r = clampi(r, 0, n - 1);
        atomicAdd(&hist[r >> BSH], 1);
    }
    __syncthreads();
    for (int i = threadIdx.x; i < NB; i += 256) {
        int v = hist[i];
        if (v) atomicAdd(&bucket_cnt[i], v);
    }
}

__global__ __launch_bounds__(1024) void bucket_scan_kernel(
    const int* __restrict__ bucket_cnt, int* __restrict__ bucket_base,
    int* __restrict__ bucket_cursor, int* __restrict__ row_ptr, int NB, int n, int E) {
    __shared__ int sh[1024];
    int t = threadIdx.x;
    int v = (t < NB) ? bucket_cnt[t] : 0;
    sh[t] = v;
    __syncthreads();
    for (int off = 1; off < 1024; off <<= 1) {
        int u = (t >= off) ? sh[t - off] : 0;
        __syncthreads();
        sh[t] += u;
        __syncthreads();
    }
    if (t < NB) {
        int base = sh[t] - v;  // exclusive
        bucket_base[t] = base;
        bucket_cursor[t] = base;
    }
    if (t == 0) row_ptr[n] = E;
}

__global__ __launch_bounds__(256) void bucket_scatter_kernel(
    const int* __restrict__ edge, const int* __restrict__ flags,
    int* __restrict__ bucket_cursor, unsigned* __restrict__ packed, int E, int n) {
    int e = blockIdx.x * 256 + threadIdx.x;
    if (e >= E) return;
    int is64 = flags[1];
    int r = is64 ? edge[2 * e] : edge[e];
    int c = is64 ? edge[2 * (E + e)] : edge[E + e];
    r = clampi(r, 0, n - 1);
    c = clampi(c, 0, n - 1);
    int p = atomicAdd(&bucket_cursor[r >> BSH], 1);
    packed[p] = ((unsigned)(r & 127) << 17) | (unsigned)c;  // col < 2^17
}

#define SORT_CAP 4096
__global__ __launch_bounds__(256) void bucket_sort_kernel(
    const unsigned* __restrict__ packed, const int* __restrict__ bucket_base,
    const int* __restrict__ bucket_cnt, int* __restrict__ row_ptr,
    int* __restrict__ col_sorted, int n) {
    __shared__ int hist[128], cur[128];
    __shared__ int out[SORT_CAP];
    int b = blockIdx.x;
    int s = bucket_base[b];
    int cnt = bucket_cnt[b];
    int t = threadIdx.x;
    if (t < 128) hist[t] = 0;
    __syncthreads();
    for (int i = t; i < cnt; i += 256) atomicAdd(&hist[packed[s + i] >> 17], 1);
    __syncthreads();
    int orig = (t < 128) ? hist[t] : 0;
    for (int off = 1; off < 128; off <<= 1) {
        int u = (t < 128 && t >= off) ? hist[t - off] : 0;
        __syncthreads();
        if (t < 128) hist[t] += u;
        __syncthreads();
    }
    if (t < 128) {
        int ex = hist[t] - orig;  // exclusive
        cur[t] = ex;
        int node = (b << BSH) + t;
        if (node < n) row_ptr[node] = s + ex;
    }
    __syncthreads();
    if (cnt <= SORT_CAP) {
        for (int i = t; i < cnt; i += 256) {
            unsigned pk = packed[s + i];
            int p = atomicAdd(&cur[pk >> 17], 1);
            out[p] = (int)(pk & 0x1FFFFu);
        }
        __syncthreads();
        for (int i = t; i < cnt; i += 256) col_sorted[s + i] = out[i];
    } else {  // overflow fallback (not expected for uniform edges)
        for (int i = t; i < cnt; i += 256) {
            unsigned pk = packed[s + i];
            int p = atomicAdd(&cur[pk >> 17], 1);
            col_sorted[s + p] = (int)(pk & 0x1FFFFu);
        }
    }
}

// ---------------- Aggregation: one node per wave, 16B/lane, 1-deep prefetch ----------------

template <int D, bool APPLY_BN, bool ADD_BIAS, bool OUT_FLAGDT>
__global__ __launch_bounds__(256) void agg_vec_kernel(
    const __hip_bfloat16* __restrict__ src, const int* __restrict__ row_ptr,
    const int* __restrict__ col_sorted, const float* __restrict__ bn_ss,
    const float* __restrict__ bias, void* __restrict__ outp,
    const int* __restrict__ flags, int n) {
    constexpr int LPR = D / 8;
    constexpr int EPW = 64 / LPR;
    int lane = threadIdx.x & 63;
    int node = blockIdx.x * 4 + (threadIdx.x >> 6);
    if (node >= n) return;
    int sub = lane / LPR;
    int c0 = (lane % LPR) * 8;

    float scale[8], shift[8];
    if (APPLY_BN) {
#pragma unroll
        for (int j = 0; j < 8; ++j) {
            scale[j] = bn_ss[c0 + j];
            shift[j] = bn_ss[128 + c0 + j];
        }
    }

    int s = row_ptr[node];
    int e = row_ptr[node + 1];
    float acc[8];
#pragma unroll
    for (int j = 0; j < 8; ++j) acc[j] = 0.f;

    int k = s + sub;
    int c = (k < e) ? col_sorted[k] : 0;
    uint4 u = *reinterpret_cast<const uint4*>(src + (size_t)c * D + c0);
    while (k < e) {
        int kn = k + EPW;
        int cn = (kn < e) ? col_sorted[kn] : 0;
        uint4 un = *reinterpret_cast<const uint4*>(src + (size_t)cn * D + c0);
        float v[8];
        v[0] = bf_lo(u.x); v[1] = bf_hi(u.x);
        v[2] = bf_lo(u.y); v[3] = bf_hi(u.y);
        v[4] = bf_lo(u.z); v[5] = bf_hi(u.z);
        v[6] = bf_lo(u.w); v[7] = bf_hi(u.w);
#pragma unroll
        for (int j = 0; j < 8; ++j) {
            if (APPLY_BN) {
                float t = fmaf(v[j], scale[j], shift[j]);
                v[j] = t > 0.f ? t : 0.f;
            }
            acc[j] += v[j];
        }
        u = un;
        k = kn;
    }
#pragma unroll
    for (int j = 0; j < 8; ++j)
#pragma unroll
        for (int off = LPR; off < 64; off <<= 1) acc[j] += __shfl_xor(acc[j], off, 64);

    if (lane < LPR) {
        float recip = 1.0f / ((float)(e - s) + 1e-6f);
        float m[8];
#pragma unroll
        for (int j = 0; j < 8; ++j) {
            m[j] = acc[j] * recip;
            if (ADD_BIAS) m[j] += bias[c0 + j];
        }
        bool as_bf = !OUT_FLAGDT || flags[0];
        if (as_bf) {
            uint4 o;
            o.x = ((unsigned)f2bf(m[1]) << 16) | f2bf(m[0]);
            o.y = ((unsigned)f2bf(m[3]) << 16) | f2bf(m[2]);
            o.z = ((unsigned)f2bf(m[5]) << 16) | f2bf(m[4]);
            o.w = ((unsigned)f2bf(m[7]) << 16) | f2bf(m[6]);
            *reinterpret_cast<uint4*>((__hip_bfloat16*)outp + (size_t)node * D + c0) = o;
        } else {
            float* op = (float*)outp + (size_t)node * D + c0;
            *reinterpret_cast<float4*>(op) = make_float4(m[0], m[1], m[2], m[3]);
            *reinterpret_cast<float4*>(op + 4) = make_float4(m[4], m[5], m[6], m[7]);
        }
    }
}

// Layer-1 agg over raw x (dtype per flags), D=64, out bf16.
__global__ __launch_bounds__(256) void agg_x_kernel(
    const void* __restrict__ xsrc, const int* __restrict__ flags,
    const int* __restrict__ row_ptr, const int* __restrict__ col_sorted,
    __hip_bfloat16* __restrict__ out, int n) {
    constexpr int D = 64, LPR = 8, EPW = 8;
    int lane = threadIdx.x & 63;
    int node = blockIdx.x * 4 + (threadIdx.x >> 6);
    if (node >= n) return;
    int sub = lane / LPR;
    int c0 = (lane % LPR) * 8;
    int s = row_ptr[node];
    int e = row_ptr[node + 1];
    float acc[8];
#pragma unroll
    for (int j = 0; j < 8; ++j) acc[j] = 0.f;

    int bf = flags[0];
    if (bf) {
        const __hip_bfloat16* xp = (const __hip_bfloat16*)xsrc;
        int k = s + sub;
        int c = (k < e) ? col_sorted[k] : 0;
        uint4 u = *reinterpret_cast<const uint4*>(xp + (size_t)c * D + c0);
        while (k < e) {
            int kn = k + EPW;
            int cn = (kn < e) ? col_sorted[kn] : 0;
            uint4 un = *reinterpret_cast<const uint4*>(xp + (size_t)cn * D + c0);
            acc[0] += bf_lo(u.x); acc[1] += bf_hi(u.x);
            acc[2] += bf_lo(u.y); acc[3] += bf_hi(u.y);
            acc[4] += bf_lo(u.z); acc[5] += bf_hi(u.z);
            acc[6] += bf_lo(u.w); acc[7] += bf_hi(u.w);
            u = un;
            k = kn;
        }
    } else {
        const float* xp = (const float*)xsrc;
        int k = s + sub;
        int c = (k < e) ? col_sorted[k] : 0;
        float4 a = *reinterpret_cast<const float4*>(xp + (size_t)c * D + c0);
        float4 b = *reinterpret_cast<const float4*>(xp + (size_t)c * D + c0 + 4);
        while (k < e) {
            int kn = k + EPW;
            int cn = (kn < e) ? col_sorted[kn] : 0;
            float4 an = *reinterpret_cast<const float4*>(xp + (size_t)cn * D + c0);
            float4 bn = *reinterpret_cast<const float4*>(xp + (size_t)cn * D + c0 + 4);
            acc[0] += a.x; acc[1] += a.y; acc[2] += a.z; acc[3] += a.w;
            acc[4] += b.x; acc[5] += b.y; acc[6] += b.z; acc[7] += b.w;
            a = an; b = bn;
            k = kn;
        }
    }
#pragma unroll
    for (int j = 0; j < 8; ++j)
#pragma unroll
        for (int off = LPR; off < 64; off <<= 1) acc[j] += __shfl_xor(acc[j], off, 64);

    if (lane < LPR) {
        float recip = 1.0f / ((float)(e - s) + 1e-6f);
        float m[8];
#pragma unroll
        for (int j = 0; j < 8; ++j) m[j] = acc[j] * recip;
        uint4 o;
        o.x = ((unsigned)f2bf(m[1]) << 16) | f2bf(m[0]);
        o.y = ((unsigned)f2bf(m[3]) << 16) | f2bf(m[2]);
        o.z = ((unsigned)f2bf(m[5]) << 16) | f2bf(m[4]);
        o.w = ((unsigned)f2bf(m[7]) << 16) | f2bf(m[6]);
        *reinterpret_cast<uint4*>(out + (size_t)node * D + c0) = o;
    }
}

// ---------------- MFMA GEMM (as R3) ----------------

__device__ __forceinline__ short8 ld_frag(const __hip_bfloat16* p) {
    union { uint4 u; short8 s; } t;
    t.u = *reinterpret_cast<const uint4*>(p);
    return t.s;
}

template <int D, int F, bool BIAS>
__global__ __launch_bounds__(256) void gemm_mfma_kernel(
    const __hip_bfloat16* __restrict__ A, const __hip_bfloat16* __restrict__ Whi,
    const __hip_bfloat16* __restrict__ Wlo, const float* __restrict__ bias,
    __hip_bfloat16* __restrict__ C, int n) {
    constexpr int JT = F / 16;
    int lane = threadIdx.x & 63;
    int wave = threadIdx.x >> 6;
    int m = lane & 15;
    int quad = lane >> 4;
    int row_base = blockIdx.x * 64 + wave * 16;

    f32x4 acc[JT];
#pragma unroll
    for (int j = 0; j < JT; ++j) acc[j] = {0.f, 0.f, 0.f, 0.f};

    const __hip_bfloat16* arow = A + (size_t)(row_base + m) * D + quad * 8;
#pragma unroll
    for (int kc = 0; kc < D; kc += 32) {
        short8 af = ld_frag(arow + kc);
#pragma unroll
        for (int jt = 0; jt < JT; ++jt) {
            const size_t wof = (size_t)(jt * 16 + m) * D + quad * 8 + kc;
            short8 bh = ld_frag(Whi + wof);
            short8 bl = ld_frag(Wlo + wof);
            acc[jt] = __builtin_amdgcn_mfma_f32_16x16x32_bf16(af, bh, acc[jt], 0, 0, 0);
            acc[jt] = __builtin_amdgcn_mfma_f32_16x16x32_bf16(af, bl, acc[jt], 0, 0, 0);
        }
    }

#pragma unroll
    for (int jt = 0; jt < JT; ++jt) {
        int col = jt * 16 + m;
        float bv = BIAS ? bias[col] : 0.f;
#pragma unroll
        for (int i = 0; i < 4; ++i) {
            int row = row_base + quad * 4 + i;
            if (row < n) {
                __hip_bfloat16 h = __float2bfloat16(acc[jt][i] + bv);
                C[(size_t)row * F + col] = h;
            }
        }
    }
}

// ---------------- BatchNorm ----------------

__global__ __launch_bounds__(256) void bn_stats_kernel(const __hip_bfloat16* __restrict__ X,
                                                       int n, float* __restrict__ sums) {
    __shared__ float red[2][16][128];
    int g = threadIdx.x & 15;
    int r0 = threadIdx.x >> 4;
    float s[8], q[8];
#pragma unroll
    for (int j = 0; j < 8; ++j) s[j] = q[j] = 0.f;
    for (int i = blockIdx.x * 16 + r0; i < n; i += gridDim.x * 16) {
        uint4 u = *reinterpret_cast<const uint4*>(X + (size_t)i * 128 + g * 8);
        float v[8];
        v[0] = bf_lo(u.x); v[1] = bf_hi(u.x);
        v[2] = bf_lo(u.y); v[3] = bf_hi(u.y);
        v[4] = bf_lo(u.z); v[5] = bf_hi(u.z);
        v[6] = bf_lo(u.w); v[7] = bf_hi(u.w);
#pragma unroll
        for (int j = 0; j < 8; ++j) {
            s[j] += v[j];
            q[j] += v[j] * v[j];
        }
    }
#pragma unroll
    for (int j = 0; j < 8; ++j) {
        red[0][r0][g * 8 + j] = s[j];
        red[1][r0][g * 8 + j] = q[j];
    }
    __syncthreads();
    for (int step = 8; step >= 1; step >>= 1) {
        if (r0 < step) {
#pragma unroll
            for (int j = 0; j < 8; ++j) {
                red[0][r0][g * 8 + j] += red[0][r0 + step][g * 8 + j];
                red[1][r0][g * 8 + j] += red[1][r0 + step][g * 8 + j];
            }
        }
        __syncthreads();
    }
    if (r0 == 0) {
#pragma unroll
        for (int j = 0; j < 8; ++j) {
            atomicAdd(&sums[g * 8 + j], red[0][0][g * 8 + j]);
            atomicAdd(&sums[128 + g * 8 + j], red[1][0][g * 8 + j]);
        }
    }
}

__global__ void bn_finalize_kernel(const float* __restrict__ sums,
                                   const float* __restrict__ gamma,
                                   const float* __restrict__ beta,
                                   float* __restrict__ ss, int n) {
    int c = threadIdx.x;  // 128
    float inv_n = 1.0f / (float)n;
    float mean = sums[c] * inv_n;
    float var = sums[128 + c] * inv_n - mean * mean;
    float inv = rsqrtf(var + 1e-5f);
    float scale = gamma[c] * inv;
    ss[c] = scale;
    ss[128 + c] = beta[c] - mean * scale;
}

__global__ __launch_bounds__(256) void bn_apply_kernel(__hip_bfloat16* __restrict__ X,
                                                       int ngroups,  // n*16
                                                       const float* __restrict__ ss) {
    __shared__ float lss[256];
    for (int i = threadIdx.x; i < 256; i += 256) lss[i] = ss[i];
    __syncthreads();
    int idx = blockIdx.x * 256 + threadIdx.x;
    int stride = gridDim.x * 256;
    for (; idx < ngroups; idx += stride) {
        int c0 = (idx & 15) * 8;
        uint4 u = *reinterpret_cast<uint4*>(X + (size_t)idx * 8);
        float v[8];
        v[0] = bf_lo(u.x); v[1] = bf_hi(u.x);
        v[2] = bf_lo(u.y); v[3] = bf_hi(u.y);
        v[4] = bf_lo(u.z); v[5] = bf_hi(u.z);
        v[6] = bf_lo(u.w); v[7] = bf_hi(u.w);
#pragma unroll
        for (int j = 0; j < 8; ++j) {
            float t = fmaf(v[j], lss[c0 + j], lss[128 + c0 + j]);
            v[j] = t > 0.f ? t : 0.f;
        }
        uint4 o;
        o.x = ((unsigned)f2bf(v[1]) << 16) | f2bf(v[0]);
        o.y = ((unsigned)f2bf(v[3]) << 16) | f2bf(v[2]);
        o.z = ((unsigned)f2bf(v[5]) << 16) | f2bf(v[4]);
        o.w = ((unsigned)f2bf(v[7]) << 16) | f2bf(v[6]);
        *reinterpret_cast<uint4*>(X + (size_t)idx * 8) = o;
    }
}

// ---------------- launch ----------------

extern "C" void kernel_launch(void* const* d_in, const int* in_sizes, int n_in,
                              void* d_out, int out_size, void* d_ws, size_t ws_size,
                              hipStream_t stream) {
    const void* x   = d_in[0];
    const int* edge = (const int*)d_in[1];

    int n = in_sizes[0] / 64;   // 100000
    int E = in_sizes[1] / 2;    // 1600000
    int NB = (n + 127) >> BSH;  // 782

    char* p = (char*)d_ws;
    auto carve = [&](size_t bytes) {
        char* q = p;
        p += (bytes + 255) & ~(size_t)255;
        return q;
    };
    int* flags      = (int*)carve(64);
    float* params   = (float*)carve(1024 * 4);
    __hip_bfloat16* Whi1 = (__hip_bfloat16*)carve(8192 * 2);
    __hip_bfloat16* Wlo1 = (__hip_bfloat16*)carve(8192 * 2);
    __hip_bfloat16* Whi2 = (__hip_bfloat16*)carve(16384 * 2);
    __hip_bfloat16* Wlo2 = (__hip_bfloat16*)carve(16384 * 2);
    __hip_bfloat16* Whi3 = (__hip_bfloat16*)carve(8192 * 2);
    __hip_bfloat16* Wlo3 = (__hip_bfloat16*)carve(8192 * 2);
    int* row_ptr    = (int*)carve((size_t)(n + 1) * 4);
    int* bucket_cnt = (int*)carve(1024 * 4);
    int* bucket_base= (int*)carve(1024 * 4);
    int* bucket_cur = (int*)carve(1024 * 4);
    float* bn_sums  = (float*)carve(256 * 4);
    float* bn_ss1   = (float*)carve(256 * 4);
    float* bn_ss2   = (float*)carve(256 * 4);
    unsigned* packed= (unsigned*)carve((size_t)E * 4);
    int* col_sorted = (int*)carve((size_t)E * 4);
    __hip_bfloat16* bufA = (__hip_bfloat16*)carve((size_t)n * 128 * 2);
    __hip_bfloat16* bufB = (__hip_bfloat16*)carve((size_t)n * 128 * 2);
    carve(65536);  // slack for boundary-block OOB A-frag reads

    float* b1f = params;        // 128
    float* g1f = b1f + 128;     // 128
    float* be1f = g1f + 128;    // 128
    float* b2f = be1f + 128;    // 128
    float* g2f = b2f + 128;     // 128
    float* be2f = g2f + 128;    // 128
    float* b3f = be2f + 128;    // 64

    detect_kernel<<<1, 1, 0, stream>>>((const unsigned int*)d_in[4], edge, flags);

    CvtPack pp;
    const int pidx[10] = {2, 3, 4, 5, 6, 7, 8, 9, 10, 11};
    void* pa[10] = {Whi1, b1f, g1f, be1f, Whi2, b2f, g2f, be2f, Whi3, b3f};
    void* pb[10] = {Wlo1, nullptr, nullptr, nullptr, Wlo2, nullptr, nullptr, nullptr, Wlo3, nullptr};
    const int psz[10] = {8192, 128, 128, 128, 16384, 128, 128, 128, 8192, 64};
    const int pmode[10] = {1, 0, 0, 0, 1, 0, 0, 0, 1, 0};
    for (int i = 0; i < 10; ++i) {
        pp.src[i] = d_in[pidx[i]];
        pp.dstA[i] = pa[i];
        pp.dstB[i] = pb[i];
        pp.sz[i] = psz[i];
        pp.mode[i] = pmode[i];
    }
    cvt_params_kernel<<<10, 256, 0, stream>>>(pp, flags);

    // CSR build via bucket sort
    hipMemsetAsync(bucket_cnt, 0, 1024 * 4, stream);
    bucket_count_kernel<<<(E + 8191) / 8192, 256, 0, stream>>>(edge, flags, bucket_cnt, E, n, NB);
    bucket_scan_kernel<<<1, 1024, 0, stream>>>(bucket_cnt, bucket_base, bucket_cur, row_ptr, NB, n, E);
    bucket_scatter_kernel<<<(E + 255) / 256, 256, 0, stream>>>(edge, flags, bucket_cur, packed, E, n);
    bucket_sort_kernel<<<NB, 256, 0, stream>>>(packed, bucket_base, bucket_cnt, row_ptr, col_sorted, n);

    int gemm_grid = (n + 63) / 64;
    int agg_grid = (n + 3) / 4;

    // Layer 1: agg(x) D=64 -> bufA ; MFMA gemm -> bufB ; BN1 stats only
    agg_x_kernel<<<agg_grid, 256, 0, stream>>>(x, flags, row_ptr, col_sorted, bufA, n);
    gemm_mfma_kernel<64, 128, true><<<gemm_grid, 256, 0, stream>>>(bufA, Whi1, Wlo1, b1f, bufB, n);
    hipMemsetAsync(bn_sums, 0, 256 * 4, stream);
    bn_stats_kernel<<<256, 256, 0, stream>>>(bufB, n, bn_sums);
    bn_finalize_kernel<<<1, 128, 0, stream>>>(bn_sums, g1f, be1f, bn_ss1, n);

    // Layer 2: agg with fused BN1-apply+ReLU -> bufA ; gemm -> bufB ; BN2 + apply
    agg_vec_kernel<128, true, false, false><<<agg_grid, 256, 0, stream>>>(
        bufB, row_ptr, col_sorted, bn_ss1, nullptr, bufA, flags, n);
    gemm_mfma_kernel<128, 128, true><<<gemm_grid, 256, 0, stream>>>(bufA, Whi2, Wlo2, b2f, bufB, n);
    hipMemsetAsync(bn_sums, 0, 256 * 4, stream);
    bn_stats_kernel<<<256, 256, 0, stream>>>(bufB, n, bn_sums);
    bn_finalize_kernel<<<1, 128, 0, stream>>>(bn_sums, g2f, be2f, bn_ss2, n);
    bn_apply_kernel<<<1024, 256, 0, stream>>>(bufB, n * 16, bn_ss2);

    // Layer 3 (reordered): gemm (no bias) -> bufA[N x 64] ; agg D=64 + bias -> d_out
    gemm_mfma_kernel<128, 64, false><<<gemm_grid, 256, 0, stream>>>(bufB, Whi3, Wlo3, nullptr, bufA, n);
    agg_vec_kernel<64, false, true, true><<<agg_grid, 256, 0, stream>>>(
        bufA, row_ptr, col_sorted, nullptr, b3f, d_out, flags, n);
}

// Round 5
// 590.559 us; speedup vs baseline: 1.6021x; 1.6021x over previous
//
#include <hip/hip_runtime.h>
#include <hip/hip_bf16.h>

// GCN: 3x (aggregate -> linear) with BN+ReLU between layers.
// R5: bucket scatter now uses block-level reservation (LDS histogram +
// one global atomicAdd per (block,bucket)) -- removes the 1.6M contended
// device-scope atomics that made R4's scatter 377us. Rest as R4.

using short8 = __attribute__((ext_vector_type(8))) short;
using f32x4  = __attribute__((ext_vector_type(4))) float;

__device__ __forceinline__ float bf_lo(unsigned int u) { return __uint_as_float(u << 16); }
__device__ __forceinline__ float bf_hi(unsigned int u) { return __uint_as_float(u & 0xffff0000u); }
__device__ __forceinline__ unsigned short f2bf(float f) {
    __hip_bfloat16 h = __float2bfloat16(f);
    return *reinterpret_cast<unsigned short*>(&h);
}
__device__ __forceinline__ int clampi(int v, int lo, int hi) {
    return v < lo ? lo : (v > hi ? hi : v);
}

#define BSH 7      // 128 nodes per bucket; NB <= 1024 for n <= 131072
#define CHUNK 8192 // edges per scatter block

// ---------------- dtype detection ----------------
// flags[0]=1 if float tensors are bf16 else fp32; flags[1]=1 if edge_index int64

__global__ void detect_kernel(const unsigned int* __restrict__ gamma_raw,
                              const int* __restrict__ edge_raw, int* __restrict__ flags) {
    if (blockIdx.x == 0 && threadIdx.x == 0) {
        flags[0] = (gamma_raw[0] == 0x3F803F80u) ? 1 : 0;
        int is64 = 1;
        for (int i = 1; i <= 15; i += 2)
            if (edge_raw[i] != 0) is64 = 0;
        flags[1] = is64;
    }
}

// ---------------- param conversion ----------------

struct CvtPack {
    const void* src[10];
    void* dstA[10];
    void* dstB[10];
    int sz[10];
    int mode[10];
};

__global__ void cvt_params_kernel(CvtPack pp, const int* __restrict__ flags) {
    int b = blockIdx.x;
    int sz = pp.sz[b];
    int bf = flags[0];
    for (int i = threadIdx.x; i < sz; i += blockDim.x) {
        float w = bf ? __bfloat162float(((const __hip_bfloat16*)pp.src[b])[i])
                     : ((const float*)pp.src[b])[i];
        if (pp.mode[b] == 0) {
            ((float*)pp.dstA[b])[i] = w;
        } else {
            __hip_bfloat16 hi = __float2bfloat16(w);
            float r = w - __bfloat162float(hi);
            ((__hip_bfloat16*)pp.dstA[b])[i] = hi;
            ((__hip_bfloat16*)pp.dstB[b])[i] = __float2bfloat16(r);
        }
    }
}

// ---------------- CSR build: bucket sort ----------------

__global__ __launch_bounds__(256) void bucket_count_kernel(
    const int* __restrict__ edge, const int* __restrict__ flags,
    int* __restrict__ bucket_cnt, int E, int n, int NB) {
    __shared__ int hist[1024];
    for (int i = threadIdx.x; i < NB; i += 256) hist[i] = 0;
    __syncthreads();
    int base = blockIdx.x * CHUNK;
    int end = base + CHUNK < E ? base + CHUNK : E;
    int is64 = flags[1];
    for (int e = base + (int)threadIdx.x; e < end; e += 256) {
        int r = is64 ? edge[2 * e] : edge[e];
        r = clampi(r, 0, n - 1);
        atomicAdd(&hist[r >> BSH], 1);
    }
    __syncthreads();
    for (int i = threadIdx.x; i < NB; i += 256) {
        int v = hist[i];
        if (v) atomicAdd(&bucket_cnt[i], v);
    }
}

__global__ __launch_bounds__(1024) void bucket_scan_kernel(
    const int* __restrict__ bucket_cnt, int* __restrict__ bucket_base,
    int* __restrict__ bucket_cursor, int* __restrict__ row_ptr, int NB, int n, int E) {
    __shared__ int sh[1024];
    int t = threadIdx.x;
    int v = (t < NB) ? bucket_cnt[t] : 0;
    sh[t] = v;
    __syncthreads();
    for (int off = 1; off < 1024; off <<= 1) {
        int u = (t >= off) ? sh[t - off] : 0;
        __syncthreads();
        sh[t] += u;
        __syncthreads();
    }
    if (t < NB) {
        int base = sh[t] - v;  // exclusive
        bucket_base[t] = base;
        bucket_cursor[t] = base;
    }
    if (t == 0) row_ptr[n] = E;
}

// Block-level reservation scatter: LDS histogram of this block's chunk,
// ONE global atomicAdd per (block,bucket) to reserve a run, then LDS-cursor
// scatter. Global atomics: ~196x782 = 153k (vs 1.6M per-edge in R4).
__global__ __launch_bounds__(256) void bucket_scatter_kernel(
    const int* __restrict__ edge, const int* __restrict__ flags,
    int* __restrict__ bucket_cursor, unsigned* __restrict__ packed,
    int E, int n, int NB) {
    __shared__ int hist[1024];
    __shared__ int cur[1024];
    int t = threadIdx.x;
    for (int i = t; i < NB; i += 256) hist[i] = 0;
    __syncthreads();
    int base = blockIdx.x * CHUNK;
    int end = base + CHUNK < E ? base + CHUNK : E;
    int is64 = flags[1];
    for (int e = base + t; e < end; e += 256) {
        int r = is64 ? edge[2 * e] : edge[e];
        r = clampi(r, 0, n - 1);
        atomicAdd(&hist[r >> BSH], 1);
    }
    __syncthreads();
    for (int i = t; i < NB; i += 256) {
        int h = hist[i];
        cur[i] = h ? atomicAdd(&bucket_cursor[i], h) : 0;
    }
    __syncthreads();
    for (int e = base + t; e < end; e += 256) {
        int r = is64 ? edge[2 * e] : edge[e];
        int c = is64 ? edge[2 * (E + e)] : edge[E + e];
        r = clampi(r, 0, n - 1);
        c = clampi(c, 0, n - 1);
        int p = atomicAdd(&cur[r >> BSH], 1);
        packed[p] = ((unsigned)(r & 127) << 17) | (unsigned)c;  // col < 2^17
    }
}

#define SORT_CAP 4096
__global__ __launch_bounds__(256) void bucket_sort_kernel(
    const unsigned* __restrict__ packed, const int* __restrict__ bucket_base,
    const int* __restrict__ bucket_cnt, int* __restrict__ row_ptr,
    int* __restrict__ col_sorted, int n) {
    __shared__ int hist[128], cur[128];
    __shared__ int out[SORT_CAP];
    int b = blockIdx.x;
    int s = bucket_base[b];
    int cnt = bucket_cnt[b];
    int t = threadIdx.x;
    if (t < 128) hist[t] = 0;
    __syncthreads();
    for (int i = t; i < cnt; i += 256) atomicAdd(&hist[packed[s + i] >> 17], 1);
    __syncthreads();
    int orig = (t < 128) ? hist[t] : 0;
    for (int off = 1; off < 128; off <<= 1) {
        int u = (t < 128 && t >= off) ? hist[t - off] : 0;
        __syncthreads();
        if (t < 128) hist[t] += u;
        __syncthreads();
    }
    if (t < 128) {
        int ex = hist[t] - orig;  // exclusive
        cur[t] = ex;
        int node = (b << BSH) + t;
        if (node < n) row_ptr[node] = s + ex;
    }
    __syncthreads();
    if (cnt <= SORT_CAP) {
        for (int i = t; i < cnt; i += 256) {
            unsigned pk = packed[s + i];
            int p = atomicAdd(&cur[pk >> 17], 1);
            out[p] = (int)(pk & 0x1FFFFu);
        }
        __syncthreads();
        for (int i = t; i < cnt; i += 256) col_sorted[s + i] = out[i];
    } else {  // overflow fallback (not expected for uniform edges)
        for (int i = t; i < cnt; i += 256) {
            unsigned pk = packed[s + i];
            int p = atomicAdd(&cur[pk >> 17], 1);
            col_sorted[s + p] = (int)(pk & 0x1FFFFu);
        }
    }
}

// ---------------- Aggregation: one node per wave, 16B/lane, 1-deep prefetch ----------------

template <int D, bool APPLY_BN, bool ADD_BIAS, bool OUT_FLAGDT>
__global__ __launch_bounds__(256) void agg_vec_kernel(
    const __hip_bfloat16* __restrict__ src, const int* __restrict__ row_ptr,
    const int* __restrict__ col_sorted, const float* __restrict__ bn_ss,
    const float* __restrict__ bias, void* __restrict__ outp,
    const int* __restrict__ flags, int n) {
    constexpr int LPR = D / 8;
    constexpr int EPW = 64 / LPR;
    int lane = threadIdx.x & 63;
    int node = blockIdx.x * 4 + (threadIdx.x >> 6);
    if (node >= n) return;
    int sub = lane / LPR;
    int c0 = (lane % LPR) * 8;

    float scale[8], shift[8];
    if (APPLY_BN) {
#pragma unroll
        for (int j = 0; j < 8; ++j) {
            scale[j] = bn_ss[c0 + j];
            shift[j] = bn_ss[128 + c0 + j];
        }
    }

    int s = row_ptr[node];
    int e = row_ptr[node + 1];
    float acc[8];
#pragma unroll
    for (int j = 0; j < 8; ++j) acc[j] = 0.f;

    int k = s + sub;
    int c = (k < e) ? col_sorted[k] : 0;
    uint4 u = *reinterpret_cast<const uint4*>(src + (size_t)c * D + c0);
    while (k < e) {
        int kn = k + EPW;
        int cn = (kn < e) ? col_sorted[kn] : 0;
        uint4 un = *reinterpret_cast<const uint4*>(src + (size_t)cn * D + c0);
        float v[8];
        v[0] = bf_lo(u.x); v[1] = bf_hi(u.x);
        v[2] = bf_lo(u.y); v[3] = bf_hi(u.y);
        v[4] = bf_lo(u.z); v[5] = bf_hi(u.z);
        v[6] = bf_lo(u.w); v[7] = bf_hi(u.w);
#pragma unroll
        for (int j = 0; j < 8; ++j) {
            if (APPLY_BN) {
                float t = fmaf(v[j], scale[j], shift[j]);
                v[j] = t > 0.f ? t : 0.f;
            }
            acc[j] += v[j];
        }
        u = un;
        k = kn;
    }
#pragma unroll
    for (int j = 0; j < 8; ++j)
#pragma unroll
        for (int off = LPR; off < 64; off <<= 1) acc[j] += __shfl_xor(acc[j], off, 64);

    if (lane < LPR) {
        float recip = 1.0f / ((float)(e - s) + 1e-6f);
        float m[8];
#pragma unroll
        for (int j = 0; j < 8; ++j) {
            m[j] = acc[j] * recip;
            if (ADD_BIAS) m[j] += bias[c0 + j];
        }
        bool as_bf = !OUT_FLAGDT || flags[0];
        if (as_bf) {
            uint4 o;
            o.x = ((unsigned)f2bf(m[1]) << 16) | f2bf(m[0]);
            o.y = ((unsigned)f2bf(m[3]) << 16) | f2bf(m[2]);
            o.z = ((unsigned)f2bf(m[5]) << 16) | f2bf(m[4]);
            o.w = ((unsigned)f2bf(m[7]) << 16) | f2bf(m[6]);
            *reinterpret_cast<uint4*>((__hip_bfloat16*)outp + (size_t)node * D + c0) = o;
        } else {
            float* op = (float*)outp + (size_t)node * D + c0;
            *reinterpret_cast<float4*>(op) = make_float4(m[0], m[1], m[2], m[3]);
            *reinterpret_cast<float4*>(op + 4) = make_float4(m[4], m[5], m[6], m[7]);
        }
    }
}

// Layer-1 agg over raw x (dtype per flags), D=64, out bf16.
__global__ __launch_bounds__(256) void agg_x_kernel(
    const void* __restrict__ xsrc, const int* __restrict__ flags,
    const int* __restrict__ row_ptr, const int* __restrict__ col_sorted,
    __hip_bfloat16* __restrict__ out, int n) {
    constexpr int D = 64, LPR = 8, EPW = 8;
    int lane = threadIdx.x & 63;
    int node = blockIdx.x * 4 + (threadIdx.x >> 6);
    if (node >= n) return;
    int sub = lane / LPR;
    int c0 = (lane % LPR) * 8;
    int s = row_ptr[node];
    int e = row_ptr[node + 1];
    float acc[8];
#pragma unroll
    for (int j = 0; j < 8; ++j) acc[j] = 0.f;

    int bf = flags[0];
    if (bf) {
        const __hip_bfloat16* xp = (const __hip_bfloat16*)xsrc;
        int k = s + sub;
        int c = (k < e) ? col_sorted[k] : 0;
        uint4 u = *reinterpret_cast<const uint4*>(xp + (size_t)c * D + c0);
        while (k < e) {
            int kn = k + EPW;
            int cn = (kn < e) ? col_sorted[kn] : 0;
            uint4 un = *reinterpret_cast<const uint4*>(xp + (size_t)cn * D + c0);
            acc[0] += bf_lo(u.x); acc[1] += bf_hi(u.x);
            acc[2] += bf_lo(u.y); acc[3] += bf_hi(u.y);
            acc[4] += bf_lo(u.z); acc[5] += bf_hi(u.z);
            acc[6] += bf_lo(u.w); acc[7] += bf_hi(u.w);
            u = un;
            k = kn;
        }
    } else {
        const float* xp = (const float*)xsrc;
        int k = s + sub;
        int c = (k < e) ? col_sorted[k] : 0;
        float4 a = *reinterpret_cast<const float4*>(xp + (size_t)c * D + c0);
        float4 b = *reinterpret_cast<const float4*>(xp + (size_t)c * D + c0 + 4);
        while (k < e) {
            int kn = k + EPW;
            int cn = (kn < e) ? col_sorted[kn] : 0;
            float4 an = *reinterpret_cast<const float4*>(xp + (size_t)cn * D + c0);
            float4 bn = *reinterpret_cast<const float4*>(xp + (size_t)cn * D + c0 + 4);
            acc[0] += a.x; acc[1] += a.y; acc[2] += a.z; acc[3] += a.w;
            acc[4] += b.x; acc[5] += b.y; acc[6] += b.z; acc[7] += b.w;
            a = an; b = bn;
            k = kn;
        }
    }
#pragma unroll
    for (int j = 0; j < 8; ++j)
#pragma unroll
        for (int off = LPR; off < 64; off <<= 1) acc[j] += __shfl_xor(acc[j], off, 64);

    if (lane < LPR) {
        float recip = 1.0f / ((float)(e - s) + 1e-6f);
        float m[8];
#pragma unroll
        for (int j = 0; j < 8; ++j) m[j] = acc[j] * recip;
        uint4 o;
        o.x = ((unsigned)f2bf(m[1]) << 16) | f2bf(m[0]);
        o.y = ((unsigned)f2bf(m[3]) << 16) | f2bf(m[2]);
        o.z = ((unsigned)f2bf(m[5]) << 16) | f2bf(m[4]);
        o.w = ((unsigned)f2bf(m[7]) << 16) | f2bf(m[6]);
        *reinterpret_cast<uint4*>(out + (size_t)node * D + c0) = o;
    }
}

// ---------------- MFMA GEMM ----------------

__device__ __forceinline__ short8 ld_frag(const __hip_bfloat16* p) {
    union { uint4 u; short8 s; } t;
    t.u = *reinterpret_cast<const uint4*>(p);
    return t.s;
}

template <int D, int F, bool BIAS>
__global__ __launch_bounds__(256) void gemm_mfma_kernel(
    const __hip_bfloat16* __restrict__ A, const __hip_bfloat16* __restrict__ Whi,
    const __hip_bfloat16* __restrict__ Wlo, const float* __restrict__ bias,
    __hip_bfloat16* __restrict__ C, int n) {
    constexpr int JT = F / 16;
    int lane = threadIdx.x & 63;
    int wave = threadIdx.x >> 6;
    int m = lane & 15;
    int quad = lane >> 4;
    int row_base = blockIdx.x * 64 + wave * 16;

    f32x4 acc[JT];
#pragma unroll
    for (int j = 0; j < JT; ++j) acc[j] = {0.f, 0.f, 0.f, 0.f};

    const __hip_bfloat16* arow = A + (size_t)(row_base + m) * D + quad * 8;
#pragma unroll
    for (int kc = 0; kc < D; kc += 32) {
        short8 af = ld_frag(arow + kc);
#pragma unroll
        for (int jt = 0; jt < JT; ++jt) {
            const size_t wof = (size_t)(jt * 16 + m) * D + quad * 8 + kc;
            short8 bh = ld_frag(Whi + wof);
            short8 bl = ld_frag(Wlo + wof);
            acc[jt] = __builtin_amdgcn_mfma_f32_16x16x32_bf16(af, bh, acc[jt], 0, 0, 0);
            acc[jt] = __builtin_amdgcn_mfma_f32_16x16x32_bf16(af, bl, acc[jt], 0, 0, 0);
        }
    }

#pragma unroll
    for (int jt = 0; jt < JT; ++jt) {
        int col = jt * 16 + m;
        float bv = BIAS ? bias[col] : 0.f;
#pragma unroll
        for (int i = 0; i < 4; ++i) {
            int row = row_base + quad * 4 + i;
            if (row < n) {
                __hip_bfloat16 h = __float2bfloat16(acc[jt][i] + bv);
                C[(size_t)row * F + col] = h;
            }
        }
    }
}

// ---------------- BatchNorm ----------------

__global__ __launch_bounds__(256) void bn_stats_kernel(const __hip_bfloat16* __restrict__ X,
                                                       int n, float* __restrict__ sums) {
    __shared__ float red[2][16][128];
    int g = threadIdx.x & 15;
    int r0 = threadIdx.x >> 4;
    float s[8], q[8];
#pragma unroll
    for (int j = 0; j < 8; ++j) s[j] = q[j] = 0.f;
    for (int i = blockIdx.x * 16 + r0; i < n; i += gridDim.x * 16) {
        uint4 u = *reinterpret_cast<const uint4*>(X + (size_t)i * 128 + g * 8);
        float v[8];
        v[0] = bf_lo(u.x); v[1] = bf_hi(u.x);
        v[2] = bf_lo(u.y); v[3] = bf_hi(u.y);
        v[4] = bf_lo(u.z); v[5] = bf_hi(u.z);
        v[6] = bf_lo(u.w); v[7] = bf_hi(u.w);
#pragma unroll
        for (int j = 0; j < 8; ++j) {
            s[j] += v[j];
            q[j] += v[j] * v[j];
        }
    }
#pragma unroll
    for (int j = 0; j < 8; ++j) {
        red[0][r0][g * 8 + j] = s[j];
        red[1][r0][g * 8 + j] = q[j];
    }
    __syncthreads();
    for (int step = 8; step >= 1; step >>= 1) {
        if (r0 < step) {
#pragma unroll
            for (int j = 0; j < 8; ++j) {
                red[0][r0][g * 8 + j] += red[0][r0 + step][g * 8 + j];
                red[1][r0][g * 8 + j] += red[1][r0 + step][g * 8 + j];
            }
        }
        __syncthreads();
    }
    if (r0 == 0) {
#pragma unroll
        for (int j = 0; j < 8; ++j) {
            atomicAdd(&sums[g * 8 + j], red[0][0][g * 8 + j]);
            atomicAdd(&sums[128 + g * 8 + j], red[1][0][g * 8 + j]);
        }
    }
}

__global__ void bn_finalize_kernel(const float* __restrict__ sums,
                                   const float* __restrict__ gamma,
                                   const float* __restrict__ beta,
                                   float* __restrict__ ss, int n) {
    int c = threadIdx.x;  // 128
    float inv_n = 1.0f / (float)n;
    float mean = sums[c] * inv_n;
    float var = sums[128 + c] * inv_n - mean * mean;
    float inv = rsqrtf(var + 1e-5f);
    float scale = gamma[c] * inv;
    ss[c] = scale;
    ss[128 + c] = beta[c] - mean * scale;
}

__global__ __launch_bounds__(256) void bn_apply_kernel(__hip_bfloat16* __restrict__ X,
                                                       int ngroups,  // n*16
                                                       const float* __restrict__ ss) {
    __shared__ float lss[256];
    for (int i = threadIdx.x; i < 256; i += 256) lss[i] = ss[i];
    __syncthreads();
    int idx = blockIdx.x * 256 + threadIdx.x;
    int stride = gridDim.x * 256;
    for (; idx < ngroups; idx += stride) {
        int c0 = (idx & 15) * 8;
        uint4 u = *reinterpret_cast<uint4*>(X + (size_t)idx * 8);
        float v[8];
        v[0] = bf_lo(u.x); v[1] = bf_hi(u.x);
        v[2] = bf_lo(u.y); v[3] = bf_hi(u.y);
        v[4] = bf_lo(u.z); v[5] = bf_hi(u.z);
        v[6] = bf_lo(u.w); v[7] = bf_hi(u.w);
#pragma unroll
        for (int j = 0; j < 8; ++j) {
            float t = fmaf(v[j], lss[c0 + j], lss[128 + c0 + j]);
            v[j] = t > 0.f ? t : 0.f;
        }
        uint4 o;
        o.x = ((unsigned)f2bf(v[1]) << 16) | f2bf(v[0]);
        o.y = ((unsigned)f2bf(v[3]) << 16) | f2bf(v[2]);
        o.z = ((unsigned)f2bf(v[5]) << 16) | f2bf(v[4]);
        o.w = ((unsigned)f2bf(v[7]) << 16) | f2bf(v[6]);
        *reinterpret_cast<uint4*>(X + (size_t)idx * 8) = o;
    }
}

// ---------------- launch ----------------

extern "C" void kernel_launch(void* const* d_in, const int* in_sizes, int n_in,
                              void* d_out, int out_size, void* d_ws, size_t ws_size,
                              hipStream_t stream) {
    const void* x   = d_in[0];
    const int* edge = (const int*)d_in[1];

    int n = in_sizes[0] / 64;   // 100000
    int E = in_sizes[1] / 2;    // 1600000
    int NB = (n + 127) >> BSH;  // 782

    char* p = (char*)d_ws;
    auto carve = [&](size_t bytes) {
        char* q = p;
        p += (bytes + 255) & ~(size_t)255;
        return q;
    };
    int* flags      = (int*)carve(64);
    float* params   = (float*)carve(1024 * 4);
    __hip_bfloat16* Whi1 = (__hip_bfloat16*)carve(8192 * 2);
    __hip_bfloat16* Wlo1 = (__hip_bfloat16*)carve(8192 * 2);
    __hip_bfloat16* Whi2 = (__hip_bfloat16*)carve(16384 * 2);
    __hip_bfloat16* Wlo2 = (__hip_bfloat16*)carve(16384 * 2);
    __hip_bfloat16* Whi3 = (__hip_bfloat16*)carve(8192 * 2);
    __hip_bfloat16* Wlo3 = (__hip_bfloat16*)carve(8192 * 2);
    int* row_ptr    = (int*)carve((size_t)(n + 1) * 4);
    int* bucket_cnt = (int*)carve(1024 * 4);
    int* bucket_base= (int*)carve(1024 * 4);
    int* bucket_cur = (int*)carve(1024 * 4);
    float* bn_sums  = (float*)carve(256 * 4);
    float* bn_ss1   = (float*)carve(256 * 4);
    float* bn_ss2   = (float*)carve(256 * 4);
    unsigned* packed= (unsigned*)carve((size_t)E * 4);
    int* col_sorted = (int*)carve((size_t)E * 4);
    __hip_bfloat16* bufA = (__hip_bfloat16*)carve((size_t)n * 128 * 2);
    __hip_bfloat16* bufB = (__hip_bfloat16*)carve((size_t)n * 128 * 2);
    carve(65536);  // slack for boundary-block OOB A-frag reads

    float* b1f = params;        // 128
    float* g1f = b1f + 128;     // 128
    float* be1f = g1f + 128;    // 128
    float* b2f = be1f + 128;    // 128
    float* g2f = b2f + 128;     // 128
    float* be2f = g2f + 128;    // 128
    float* b3f = be2f + 128;    // 64

    detect_kernel<<<1, 1, 0, stream>>>((const unsigned int*)d_in[4], edge, flags);

    CvtPack pp;
    const int pidx[10] = {2, 3, 4, 5, 6, 7, 8, 9, 10, 11};
    void* pa[10] = {Whi1, b1f, g1f, be1f, Whi2, b2f, g2f, be2f, Whi3, b3f};
    void* pb[10] = {Wlo1, nullptr, nullptr, nullptr, Wlo2, nullptr, nullptr, nullptr, Wlo3, nullptr};
    const int psz[10] = {8192, 128, 128, 128, 16384, 128, 128, 128, 8192, 64};
    const int pmode[10] = {1, 0, 0, 0, 1, 0, 0, 0, 1, 0};
    for (int i = 0; i < 10; ++i) {
        pp.src[i] = d_in[pidx[i]];
        pp.dstA[i] = pa[i];
        pp.dstB[i] = pb[i];
        pp.sz[i] = psz[i];
        pp.mode[i] = pmode[i];
    }
    cvt_params_kernel<<<10, 256, 0, stream>>>(pp, flags);

    // CSR build via bucket sort (block-reservation scatter)
    hipMemsetAsync(bucket_cnt, 0, 1024 * 4, stream);
    int nchunks = (E + CHUNK - 1) / CHUNK;
    bucket_count_kernel<<<nchunks, 256, 0, stream>>>(edge, flags, bucket_cnt, E, n, NB);
    bucket_scan_kernel<<<1, 1024, 0, stream>>>(bucket_cnt, bucket_base, bucket_cur, row_ptr, NB, n, E);
    bucket_scatter_kernel<<<nchunks, 256, 0, stream>>>(edge, flags, bucket_cur, packed, E, n, NB);
    bucket_sort_kernel<<<NB, 256, 0, stream>>>(packed, bucket_base, bucket_cnt, row_ptr, col_sorted, n);

    int gemm_grid = (n + 63) / 64;
    int agg_grid = (n + 3) / 4;

    // Layer 1: agg(x) D=64 -> bufA ; MFMA gemm -> bufB ; BN1 stats only
    agg_x_kernel<<<agg_grid, 256, 0, stream>>>(x, flags, row_ptr, col_sorted, bufA, n);
    gemm_mfma_kernel<64, 128, true><<<gemm_grid, 256, 0, stream>>>(bufA, Whi1, Wlo1, b1f, bufB, n);
    hipMemsetAsync(bn_sums, 0, 256 * 4, stream);
    bn_stats_kernel<<<256, 256, 0, stream>>>(bufB, n, bn_sums);
    bn_finalize_kernel<<<1, 128, 0, stream>>>(bn_sums, g1f, be1f, bn_ss1, n);

    // Layer 2: agg with fused BN1-apply+ReLU -> bufA ; gemm -> bufB ; BN2 + apply
    agg_vec_kernel<128, true, false, false><<<agg_grid, 256, 0, stream>>>(
        bufB, row_ptr, col_sorted, bn_ss1, nullptr, bufA, flags, n);
    gemm_mfma_kernel<128, 128, true><<<gemm_grid, 256, 0, stream>>>(bufA, Whi2, Wlo2, b2f, bufB, n);
    hipMemsetAsync(bn_sums, 0, 256 * 4, stream);
    bn_stats_kernel<<<256, 256, 0, stream>>>(bufB, n, bn_sums);
    bn_finalize_kernel<<<1, 128, 0, stream>>>(bn_sums, g2f, be2f, bn_ss2, n);
    bn_apply_kernel<<<1024, 256, 0, stream>>>(bufB, n * 16, bn_ss2);

    // Layer 3 (reordered): gemm (no bias) -> bufA[N x 64] ; agg D=64 + bias -> d_out
    gemm_mfma_kernel<128, 64, false><<<gemm_grid, 256, 0, stream>>>(bufB, Whi3, Wlo3, nullptr, bufA, n);
    agg_vec_kernel<64, false, true, true><<<agg_grid, 256, 0, stream>>>(
        bufA, row_ptr, col_sorted, nullptr, b3f, d_out, flags, n);
}

// Round 6
// 523.862 us; speedup vs baseline: 1.8061x; 1.1273x over previous
//
#include <hip/hip_runtime.h>
#include <hip/hip_bf16.h>

// GCN: 3x (aggregate -> linear) with BN+ReLU between layers.
// R6: GEMM rewritten -- W (hi+lo split) staged once per block into LDS,
// pre-swizzled into MFMA fragment order so ds_read_b128 is lane-contiguous
// (conflict-free). A-frags prefetched to registers. 128 rows/block,
// 32 rows/wave. R5's GEMM was latency-bound (MfmaUtil 3.3%) on per-wave
// global W loads. CSR bucket sort + vectorized agg as R5.

using short8 = __attribute__((ext_vector_type(8))) short;
using f32x4  = __attribute__((ext_vector_type(4))) float;

__device__ __forceinline__ float bf_lo(unsigned int u) { return __uint_as_float(u << 16); }
__device__ __forceinline__ float bf_hi(unsigned int u) { return __uint_as_float(u & 0xffff0000u); }
__device__ __forceinline__ unsigned short f2bf(float f) {
    __hip_bfloat16 h = __float2bfloat16(f);
    return *reinterpret_cast<unsigned short*>(&h);
}
__device__ __forceinline__ int clampi(int v, int lo, int hi) {
    return v < lo ? lo : (v > hi ? hi : v);
}

#define BSH 7      // 128 nodes per bucket; NB <= 1024 for n <= 131072
#define CHUNK 8192 // edges per scatter block

// ---------------- dtype detection ----------------
// flags[0]=1 if float tensors are bf16 else fp32; flags[1]=1 if edge_index int64

__global__ void detect_kernel(const unsigned int* __restrict__ gamma_raw,
                              const int* __restrict__ edge_raw, int* __restrict__ flags) {
    if (blockIdx.x == 0 && threadIdx.x == 0) {
        flags[0] = (gamma_raw[0] == 0x3F803F80u) ? 1 : 0;
        int is64 = 1;
        for (int i = 1; i <= 15; i += 2)
            if (edge_raw[i] != 0) is64 = 0;
        flags[1] = is64;
    }
}

// ---------------- param conversion ----------------

struct CvtPack {
    const void* src[10];
    void* dstA[10];
    void* dstB[10];
    int sz[10];
    int mode[10];
};

__global__ void cvt_params_kernel(CvtPack pp, const int* __restrict__ flags) {
    int b = blockIdx.x;
    int sz = pp.sz[b];
    int bf = flags[0];
    for (int i = threadIdx.x; i < sz; i += blockDim.x) {
        float w = bf ? __bfloat162float(((const __hip_bfloat16*)pp.src[b])[i])
                     : ((const float*)pp.src[b])[i];
        if (pp.mode[b] == 0) {
            ((float*)pp.dstA[b])[i] = w;
        } else {
            __hip_bfloat16 hi = __float2bfloat16(w);
            float r = w - __bfloat162float(hi);
            ((__hip_bfloat16*)pp.dstA[b])[i] = hi;
            ((__hip_bfloat16*)pp.dstB[b])[i] = __float2bfloat16(r);
        }
    }
}

// ---------------- CSR build: bucket sort ----------------

__global__ __launch_bounds__(256) void bucket_count_kernel(
    const int* __restrict__ edge, const int* __restrict__ flags,
    int* __restrict__ bucket_cnt, int E, int n, int NB) {
    __shared__ int hist[1024];
    for (int i = threadIdx.x; i < NB; i += 256) hist[i] = 0;
    __syncthreads();
    int base = blockIdx.x * CHUNK;
    int end = base + CHUNK < E ? base + CHUNK : E;
    int is64 = flags[1];
    for (int e = base + (int)threadIdx.x; e < end; e += 256) {
        int r = is64 ? edge[2 * e] : edge[e];
        r = clampi(r, 0, n - 1);
        atomicAdd(&hist[r >> BSH], 1);
    }
    __syncthreads();
    for (int i = threadIdx.x; i < NB; i += 256) {
        int v = hist[i];
        if (v) atomicAdd(&bucket_cnt[i], v);
    }
}

__global__ __launch_bounds__(1024) void bucket_scan_kernel(
    const int* __restrict__ bucket_cnt, int* __restrict__ bucket_base,
    int* __restrict__ bucket_cursor, int* __restrict__ row_ptr, int NB, int n, int E) {
    __shared__ int sh[1024];
    int t = threadIdx.x;
    int v = (t < NB) ? bucket_cnt[t] : 0;
    sh[t] = v;
    __syncthreads();
    for (int off = 1; off < 1024; off <<= 1) {
        int u = (t >= off) ? sh[t - off] : 0;
        __syncthreads();
        sh[t] += u;
        __syncthreads();
    }
    if (t < NB) {
        int base = sh[t] - v;  // exclusive
        bucket_base[t] = base;
        bucket_cursor[t] = base;
    }
    if (t == 0) row_ptr[n] = E;
}

// Block-level reservation scatter (one global atomicAdd per block,bucket).
__global__ __launch_bounds__(256) void bucket_scatter_kernel(
    const int* __restrict__ edge, const int* __restrict__ flags,
    int* __restrict__ bucket_cursor, unsigned* __restrict__ packed,
    int E, int n, int NB) {
    __shared__ int hist[1024];
    __shared__ int cur[1024];
    int t = threadIdx.x;
    for (int i = t; i < NB; i += 256) hist[i] = 0;
    __syncthreads();
    int base = blockIdx.x * CHUNK;
    int end = base + CHUNK < E ? base + CHUNK : E;
    int is64 = flags[1];
    for (int e = base + t; e < end; e += 256) {
        int r = is64 ? edge[2 * e] : edge[e];
        r = clampi(r, 0, n - 1);
        atomicAdd(&hist[r >> BSH], 1);
    }
    __syncthreads();
    for (int i = t; i < NB; i += 256) {
        int h = hist[i];
        cur[i] = h ? atomicAdd(&bucket_cursor[i], h) : 0;
    }
    __syncthreads();
    for (int e = base + t; e < end; e += 256) {
        int r = is64 ? edge[2 * e] : edge[e];
        int c = is64 ? edge[2 * (E + e)] : edge[E + e];
        r = clampi(r, 0, n - 1);
        c = clampi(c, 0, n - 1);
        int p = atomicAdd(&cur[r >> BSH], 1);
        packed[p] = ((unsigned)(r & 127) << 17) | (unsigned)c;  // col < 2^17
    }
}

#define SORT_CAP 4096
__global__ __launch_bounds__(256) void bucket_sort_kernel(
    const unsigned* __restrict__ packed, const int* __restrict__ bucket_base,
    const int* __restrict__ bucket_cnt, int* __restrict__ row_ptr,
    int* __restrict__ col_sorted, int n) {
    __shared__ int hist[128], cur[128];
    __shared__ int out[SORT_CAP];
    int b = blockIdx.x;
    int s = bucket_base[b];
    int cnt = bucket_cnt[b];
    int t = threadIdx.x;
    if (t < 128) hist[t] = 0;
    __syncthreads();
    for (int i = t; i < cnt; i += 256) atomicAdd(&hist[packed[s + i] >> 17], 1);
    __syncthreads();
    int orig = (t < 128) ? hist[t] : 0;
    for (int off = 1; off < 128; off <<= 1) {
        int u = (t < 128 && t >= off) ? hist[t - off] : 0;
        __syncthreads();
        if (t < 128) hist[t] += u;
        __syncthreads();
    }
    if (t < 128) {
        int ex = hist[t] - orig;  // exclusive
        cur[t] = ex;
        int node = (b << BSH) + t;
        if (node < n) row_ptr[node] = s + ex;
    }
    __syncthreads();
    if (cnt <= SORT_CAP) {
        for (int i = t; i < cnt; i += 256) {
            unsigned pk = packed[s + i];
            int p = atomicAdd(&cur[pk >> 17], 1);
            out[p] = (int)(pk & 0x1FFFFu);
        }
        __syncthreads();
        for (int i = t; i < cnt; i += 256) col_sorted[s + i] = out[i];
    } else {  // overflow fallback
        for (int i = t; i < cnt; i += 256) {
            unsigned pk = packed[s + i];
            int p = atomicAdd(&cur[pk >> 17], 1);
            col_sorted[s + p] = (int)(pk & 0x1FFFFu);
        }
    }
}

// ---------------- Aggregation: one node per wave, 16B/lane, 1-deep prefetch ----------------

template <int D, bool APPLY_BN, bool ADD_BIAS, bool OUT_FLAGDT>
__global__ __launch_bounds__(256) void agg_vec_kernel(
    const __hip_bfloat16* __restrict__ src, const int* __restrict__ row_ptr,
    const int* __restrict__ col_sorted, const float* __restrict__ bn_ss,
    const float* __restrict__ bias, void* __restrict__ outp,
    const int* __restrict__ flags, int n) {
    constexpr int LPR = D / 8;
    constexpr int EPW = 64 / LPR;
    int lane = threadIdx.x & 63;
    int node = blockIdx.x * 4 + (threadIdx.x >> 6);
    if (node >= n) return;
    int sub = lane / LPR;
    int c0 = (lane % LPR) * 8;

    float scale[8], shift[8];
    if (APPLY_BN) {
#pragma unroll
        for (int j = 0; j < 8; ++j) {
            scale[j] = bn_ss[c0 + j];
            shift[j] = bn_ss[128 + c0 + j];
        }
    }

    int s = row_ptr[node];
    int e = row_ptr[node + 1];
    float acc[8];
#pragma unroll
    for (int j = 0; j < 8; ++j) acc[j] = 0.f;

    int k = s + sub;
    int c = (k < e) ? col_sorted[k] : 0;
    uint4 u = *reinterpret_cast<const uint4*>(src + (size_t)c * D + c0);
    while (k < e) {
        int kn = k + EPW;
        int cn = (kn < e) ? col_sorted[kn] : 0;
        uint4 un = *reinterpret_cast<const uint4*>(src + (size_t)cn * D + c0);
        float v[8];
        v[0] = bf_lo(u.x); v[1] = bf_hi(u.x);
        v[2] = bf_lo(u.y); v[3] = bf_hi(u.y);
        v[4] = bf_lo(u.z); v[5] = bf_hi(u.z);
        v[6] = bf_lo(u.w); v[7] = bf_hi(u.w);
#pragma unroll
        for (int j = 0; j < 8; ++j) {
            if (APPLY_BN) {
                float t = fmaf(v[j], scale[j], shift[j]);
                v[j] = t > 0.f ? t : 0.f;
            }
            acc[j] += v[j];
        }
        u = un;
        k = kn;
    }
#pragma unroll
    for (int j = 0; j < 8; ++j)
#pragma unroll
        for (int off = LPR; off < 64; off <<= 1) acc[j] += __shfl_xor(acc[j], off, 64);

    if (lane < LPR) {
        float recip = 1.0f / ((float)(e - s) + 1e-6f);
        float m[8];
#pragma unroll
        for (int j = 0; j < 8; ++j) {
            m[j] = acc[j] * recip;
            if (ADD_BIAS) m[j] += bias[c0 + j];
        }
        bool as_bf = !OUT_FLAGDT || flags[0];
        if (as_bf) {
            uint4 o;
            o.x = ((unsigned)f2bf(m[1]) << 16) | f2bf(m[0]);
            o.y = ((unsigned)f2bf(m[3]) << 16) | f2bf(m[2]);
            o.z = ((unsigned)f2bf(m[5]) << 16) | f2bf(m[4]);
            o.w = ((unsigned)f2bf(m[7]) << 16) | f2bf(m[6]);
            *reinterpret_cast<uint4*>((__hip_bfloat16*)outp + (size_t)node * D + c0) = o;
        } else {
            float* op = (float*)outp + (size_t)node * D + c0;
            *reinterpret_cast<float4*>(op) = make_float4(m[0], m[1], m[2], m[3]);
            *reinterpret_cast<float4*>(op + 4) = make_float4(m[4], m[5], m[6], m[7]);
        }
    }
}

// Layer-1 agg over raw x (dtype per flags), D=64, out bf16.
__global__ __launch_bounds__(256) void agg_x_kernel(
    const void* __restrict__ xsrc, const int* __restrict__ flags,
    const int* __restrict__ row_ptr, const int* __restrict__ col_sorted,
    __hip_bfloat16* __restrict__ out, int n) {
    constexpr int D = 64, LPR = 8, EPW = 8;
    int lane = threadIdx.x & 63;
    int node = blockIdx.x * 4 + (threadIdx.x >> 6);
    if (node >= n) return;
    int sub = lane / LPR;
    int c0 = (lane % LPR) * 8;
    int s = row_ptr[node];
    int e = row_ptr[node + 1];
    float acc[8];
#pragma unroll
    for (int j = 0; j < 8; ++j) acc[j] = 0.f;

    int bf = flags[0];
    if (bf) {
        const __hip_bfloat16* xp = (const __hip_bfloat16*)xsrc;
        int k = s + sub;
        int c = (k < e) ? col_sorted[k] : 0;
        uint4 u = *reinterpret_cast<const uint4*>(xp + (size_t)c * D + c0);
        while (k < e) {
            int kn = k + EPW;
            int cn = (kn < e) ? col_sorted[kn] : 0;
            uint4 un = *reinterpret_cast<const uint4*>(xp + (size_t)cn * D + c0);
            acc[0] += bf_lo(u.x); acc[1] += bf_hi(u.x);
            acc[2] += bf_lo(u.y); acc[3] += bf_hi(u.y);
            acc[4] += bf_lo(u.z); acc[5] += bf_hi(u.z);
            acc[6] += bf_lo(u.w); acc[7] += bf_hi(u.w);
            u = un;
            k = kn;
        }
    } else {
        const float* xp = (const float*)xsrc;
        int k = s + sub;
        int c = (k < e) ? col_sorted[k] : 0;
        float4 a = *reinterpret_cast<const float4*>(xp + (size_t)c * D + c0);
        float4 b = *reinterpret_cast<const float4*>(xp + (size_t)c * D + c0 + 4);
        while (k < e) {
            int kn = k + EPW;
            int cn = (kn < e) ? col_sorted[kn] : 0;
            float4 an = *reinterpret_cast<const float4*>(xp + (size_t)cn * D + c0);
            float4 bn = *reinterpret_cast<const float4*>(xp + (size_t)cn * D + c0 + 4);
            acc[0] += a.x; acc[1] += a.y; acc[2] += a.z; acc[3] += a.w;
            acc[4] += b.x; acc[5] += b.y; acc[6] += b.z; acc[7] += b.w;
            a = an; b = bn;
            k = kn;
        }
    }
#pragma unroll
    for (int j = 0; j < 8; ++j)
#pragma unroll
        for (int off = LPR; off < 64; off <<= 1) acc[j] += __shfl_xor(acc[j], off, 64);

    if (lane < LPR) {
        float recip = 1.0f / ((float)(e - s) + 1e-6f);
        float m[8];
#pragma unroll
        for (int j = 0; j < 8; ++j) m[j] = acc[j] * recip;
        uint4 o;
        o.x = ((unsigned)f2bf(m[1]) << 16) | f2bf(m[0]);
        o.y = ((unsigned)f2bf(m[3]) << 16) | f2bf(m[2]);
        o.z = ((unsigned)f2bf(m[5]) << 16) | f2bf(m[4]);
        o.w = ((unsigned)f2bf(m[7]) << 16) | f2bf(m[6]);
        *reinterpret_cast<uint4*>(out + (size_t)node * D + c0) = o;
    }
}

// ---------------- MFMA GEMM, LDS-staged W ----------------
// Block: 256 thr = 4 waves, 128 rows (32 rows/wave as 2 rowsets of 16).
// W (hi+lo) staged once into LDS in FRAGMENT order: frag f=(kc*JT+jt)*2+h,
// lane-contiguous 16B chunks -> ds_read_b128 conflict-free.
// A-frags prefetched to registers before the K-loop.

template <int D, int F, bool BIAS>
__global__ __launch_bounds__(256) void gemm_mfma_kernel(
    const __hip_bfloat16* __restrict__ A, const __hip_bfloat16* __restrict__ Whi,
    const __hip_bfloat16* __restrict__ Wlo, const float* __restrict__ bias,
    __hip_bfloat16* __restrict__ C, int n) {
    constexpr int JT = F / 16;
    constexpr int KCH = D / 32;
    constexpr int NF = KCH * JT * 2;       // fragments (hi+lo)
    __shared__ uint4 wlds[NF * 64];        // NF KB; max 64 KB (D=128,F=128)

    int t = threadIdx.x;
    // cooperative fill, fragment order
    for (int idx = t; idx < NF * 64; idx += 256) {
        int f = idx >> 6, ln = idx & 63;
        int kc = f / (JT * 2);
        int rem = f % (JT * 2);
        int jt = rem >> 1, h = rem & 1;
        int mm = ln & 15, qq = ln >> 4;
        const __hip_bfloat16* src =
            (h ? Wlo : Whi) + (size_t)(jt * 16 + mm) * D + kc * 32 + qq * 8;
        wlds[idx] = *reinterpret_cast<const uint4*>(src);
    }

    int lane = t & 63;
    int wave = t >> 6;
    int m = lane & 15;
    int quad = lane >> 4;
    int row_base = blockIdx.x * 128 + wave * 32;

    // prefetch A-frags (2 rowsets x KCH chunks)
    short8 af[2][KCH];
#pragma unroll
    for (int rs = 0; rs < 2; ++rs) {
        int r = row_base + rs * 16 + m;
        r = r < n ? r : n - 1;
        const __hip_bfloat16* ap = A + (size_t)r * D + quad * 8;
#pragma unroll
        for (int kc = 0; kc < KCH; ++kc) {
            union { uint4 u; short8 s; } tmp;
            tmp.u = *reinterpret_cast<const uint4*>(ap + kc * 32);
            af[rs][kc] = tmp.s;
        }
    }

    f32x4 acc[2][JT];
#pragma unroll
    for (int rs = 0; rs < 2; ++rs)
#pragma unroll
        for (int j = 0; j < JT; ++j) acc[rs][j] = {0.f, 0.f, 0.f, 0.f};

    __syncthreads();

#pragma unroll
    for (int kc = 0; kc < KCH; ++kc) {
#pragma unroll
        for (int jt = 0; jt < JT; ++jt) {
            int fb = (kc * JT + jt) * 2;
            union { uint4 u; short8 s; } bh, bl;
            bh.u = wlds[fb * 64 + lane];
            bl.u = wlds[(fb + 1) * 64 + lane];
            acc[0][jt] = __builtin_amdgcn_mfma_f32_16x16x32_bf16(af[0][kc], bh.s, acc[0][jt], 0, 0, 0);
            acc[1][jt] = __builtin_amdgcn_mfma_f32_16x16x32_bf16(af[1][kc], bh.s, acc[1][jt], 0, 0, 0);
            acc[0][jt] = __builtin_amdgcn_mfma_f32_16x16x32_bf16(af[0][kc], bl.s, acc[0][jt], 0, 0, 0);
            acc[1][jt] = __builtin_amdgcn_mfma_f32_16x16x32_bf16(af[1][kc], bl.s, acc[1][jt], 0, 0, 0);
        }
    }

#pragma unroll
    for (int rs = 0; rs < 2; ++rs) {
#pragma unroll
        for (int jt = 0; jt < JT; ++jt) {
            int col = jt * 16 + m;
            float bv = BIAS ? bias[col] : 0.f;
#pragma unroll
            for (int i = 0; i < 4; ++i) {
                int row = row_base + rs * 16 + quad * 4 + i;
                if (row < n)
                    C[(size_t)row * F + col] = __float2bfloat16(acc[rs][jt][i] + bv);
            }
        }
    }
}

// ---------------- BatchNorm ----------------

__global__ __launch_bounds__(256) void bn_stats_kernel(const __hip_bfloat16* __restrict__ X,
                                                       int n, float* __restrict__ sums) {
    __shared__ float red[2][16][128];
    int g = threadIdx.x & 15;
    int r0 = threadIdx.x >> 4;
    float s[8], q[8];
#pragma unroll
    for (int j = 0; j < 8; ++j) s[j] = q[j] = 0.f;
    for (int i = blockIdx.x * 16 + r0; i < n; i += gridDim.x * 16) {
        uint4 u = *reinterpret_cast<const uint4*>(X + (size_t)i * 128 + g * 8);
        float v[8];
        v[0] = bf_lo(u.x); v[1] = bf_hi(u.x);
        v[2] = bf_lo(u.y); v[3] = bf_hi(u.y);
        v[4] = bf_lo(u.z); v[5] = bf_hi(u.z);
        v[6] = bf_lo(u.w); v[7] = bf_hi(u.w);
#pragma unroll
        for (int j = 0; j < 8; ++j) {
            s[j] += v[j];
            q[j] += v[j] * v[j];
        }
    }
#pragma unroll
    for (int j = 0; j < 8; ++j) {
        red[0][r0][g * 8 + j] = s[j];
        red[1][r0][g * 8 + j] = q[j];
    }
    __syncthreads();
    for (int step = 8; step >= 1; step >>= 1) {
        if (r0 < step) {
#pragma unroll
            for (int j = 0; j < 8; ++j) {
                red[0][r0][g * 8 + j] += red[0][r0 + step][g * 8 + j];
                red[1][r0][g * 8 + j] += red[1][r0 + step][g * 8 + j];
            }
        }
        __syncthreads();
    }
    if (r0 == 0) {
#pragma unroll
        for (int j = 0; j < 8; ++j) {
            atomicAdd(&sums[g * 8 + j], red[0][0][g * 8 + j]);
            atomicAdd(&sums[128 + g * 8 + j], red[1][0][g * 8 + j]);
        }
    }
}

__global__ void bn_finalize_kernel(const float* __restrict__ sums,
                                   const float* __restrict__ gamma,
                                   const float* __restrict__ beta,
                                   float* __restrict__ ss, int n) {
    int c = threadIdx.x;  // 128
    float inv_n = 1.0f / (float)n;
    float mean = sums[c] * inv_n;
    float var = sums[128 + c] * inv_n - mean * mean;
    float inv = rsqrtf(var + 1e-5f);
    float scale = gamma[c] * inv;
    ss[c] = scale;
    ss[128 + c] = beta[c] - mean * scale;
}

__global__ __launch_bounds__(256) void bn_apply_kernel(__hip_bfloat16* __restrict__ X,
                                                       int ngroups,  // n*16
                                                       const float* __restrict__ ss) {
    __shared__ float lss[256];
    for (int i = threadIdx.x; i < 256; i += 256) lss[i] = ss[i];
    __syncthreads();
    int idx = blockIdx.x * 256 + threadIdx.x;
    int stride = gridDim.x * 256;
    for (; idx < ngroups; idx += stride) {
        int c0 = (idx & 15) * 8;
        uint4 u = *reinterpret_cast<uint4*>(X + (size_t)idx * 8);
        float v[8];
        v[0] = bf_lo(u.x); v[1] = bf_hi(u.x);
        v[2] = bf_lo(u.y); v[3] = bf_hi(u.y);
        v[4] = bf_lo(u.z); v[5] = bf_hi(u.z);
        v[6] = bf_lo(u.w); v[7] = bf_hi(u.w);
#pragma unroll
        for (int j = 0; j < 8; ++j) {
            float t = fmaf(v[j], lss[c0 + j], lss[128 + c0 + j]);
            v[j] = t > 0.f ? t : 0.f;
        }
        uint4 o;
        o.x = ((unsigned)f2bf(v[1]) << 16) | f2bf(v[0]);
        o.y = ((unsigned)f2bf(v[3]) << 16) | f2bf(v[2]);
        o.z = ((unsigned)f2bf(v[5]) << 16) | f2bf(v[4]);
        o.w = ((unsigned)f2bf(v[7]) << 16) | f2bf(v[6]);
        *reinterpret_cast<uint4*>(X + (size_t)idx * 8) = o;
    }
}

// ---------------- launch ----------------

extern "C" void kernel_launch(void* const* d_in, const int* in_sizes, int n_in,
                              void* d_out, int out_size, void* d_ws, size_t ws_size,
                              hipStream_t stream) {
    const void* x   = d_in[0];
    const int* edge = (const int*)d_in[1];

    int n = in_sizes[0] / 64;   // 100000
    int E = in_sizes[1] / 2;    // 1600000
    int NB = (n + 127) >> BSH;  // 782

    char* p = (char*)d_ws;
    auto carve = [&](size_t bytes) {
        char* q = p;
        p += (bytes + 255) & ~(size_t)255;
        return q;
    };
    int* flags      = (int*)carve(64);
    float* params   = (float*)carve(1024 * 4);
    __hip_bfloat16* Whi1 = (__hip_bfloat16*)carve(8192 * 2);
    __hip_bfloat16* Wlo1 = (__hip_bfloat16*)carve(8192 * 2);
    __hip_bfloat16* Whi2 = (__hip_bfloat16*)carve(16384 * 2);
    __hip_bfloat16* Wlo2 = (__hip_bfloat16*)carve(16384 * 2);
    __hip_bfloat16* Whi3 = (__hip_bfloat16*)carve(8192 * 2);
    __hip_bfloat16* Wlo3 = (__hip_bfloat16*)carve(8192 * 2);
    int* row_ptr    = (int*)carve((size_t)(n + 1) * 4);
    int* bucket_cnt = (int*)carve(1024 * 4);
    int* bucket_base= (int*)carve(1024 * 4);
    int* bucket_cur = (int*)carve(1024 * 4);
    float* bn_sums  = (float*)carve(256 * 4);
    float* bn_ss1   = (float*)carve(256 * 4);
    float* bn_ss2   = (float*)carve(256 * 4);
    unsigned* packed= (unsigned*)carve((size_t)E * 4);
    int* col_sorted = (int*)carve((size_t)E * 4);
    __hip_bfloat16* bufA = (__hip_bfloat16*)carve((size_t)n * 128 * 2);
    __hip_bfloat16* bufB = (__hip_bfloat16*)carve((size_t)n * 128 * 2);
    carve(65536);  // slack

    float* b1f = params;        // 128
    float* g1f = b1f + 128;     // 128
    float* be1f = g1f + 128;    // 128
    float* b2f = be1f + 128;    // 128
    float* g2f = b2f + 128;     // 128
    float* be2f = g2f + 128;    // 128
    float* b3f = be2f + 128;    // 64

    detect_kernel<<<1, 1, 0, stream>>>((const unsigned int*)d_in[4], edge, flags);

    CvtPack pp;
    const int pidx[10] = {2, 3, 4, 5, 6, 7, 8, 9, 10, 11};
    void* pa[10] = {Whi1, b1f, g1f, be1f, Whi2, b2f, g2f, be2f, Whi3, b3f};
    void* pb[10] = {Wlo1, nullptr, nullptr, nullptr, Wlo2, nullptr, nullptr, nullptr, Wlo3, nullptr};
    const int psz[10] = {8192, 128, 128, 128, 16384, 128, 128, 128, 8192, 64};
    const int pmode[10] = {1, 0, 0, 0, 1, 0, 0, 0, 1, 0};
    for (int i = 0; i < 10; ++i) {
        pp.src[i] = d_in[pidx[i]];
        pp.dstA[i] = pa[i];
        pp.dstB[i] = pb[i];
        pp.sz[i] = psz[i];
        pp.mode[i] = pmode[i];
    }
    cvt_params_kernel<<<10, 256, 0, stream>>>(pp, flags);

    // CSR build via bucket sort (block-reservation scatter)
    hipMemsetAsync(bucket_cnt, 0, 1024 * 4, stream);
    int nchunks = (E + CHUNK - 1) / CHUNK;
    bucket_count_kernel<<<nchunks, 256, 0, stream>>>(edge, flags, bucket_cnt, E, n, NB);
    bucket_scan_kernel<<<1, 1024, 0, stream>>>(bucket_cnt, bucket_base, bucket_cur, row_ptr, NB, n, E);
    bucket_scatter_kernel<<<nchunks, 256, 0, stream>>>(edge, flags, bucket_cur, packed, E, n, NB);
    bucket_sort_kernel<<<NB, 256, 0, stream>>>(packed, bucket_base, bucket_cnt, row_ptr, col_sorted, n);

    int gemm_grid = (n + 127) / 128;
    int agg_grid = (n + 3) / 4;

    // Layer 1: agg(x) D=64 -> bufA ; MFMA gemm -> bufB ; BN1 stats only
    agg_x_kernel<<<agg_grid, 256, 0, stream>>>(x, flags, row_ptr, col_sorted, bufA, n);
    gemm_mfma_kernel<64, 128, true><<<gemm_grid, 256, 0, stream>>>(bufA, Whi1, Wlo1, b1f, bufB, n);
    hipMemsetAsync(bn_sums, 0, 256 * 4, stream);
    bn_stats_kernel<<<256, 256, 0, stream>>>(bufB, n, bn_sums);
    bn_finalize_kernel<<<1, 128, 0, stream>>>(bn_sums, g1f, be1f, bn_ss1, n);

    // Layer 2: agg with fused BN1-apply+ReLU -> bufA ; gemm -> bufB ; BN2 + apply
    agg_vec_kernel<128, true, false, false><<<agg_grid, 256, 0, stream>>>(
        bufB, row_ptr, col_sorted, bn_ss1, nullptr, bufA, flags, n);
    gemm_mfma_kernel<128, 128, true><<<gemm_grid, 256, 0, stream>>>(bufA, Whi2, Wlo2, b2f, bufB, n);
    hipMemsetAsync(bn_sums, 0, 256 * 4, stream);
    bn_stats_kernel<<<256, 256, 0, stream>>>(bufB, n, bn_sums);
    bn_finalize_kernel<<<1, 128, 0, stream>>>(bn_sums, g2f, be2f, bn_ss2, n);
    bn_apply_kernel<<<1024, 256, 0, stream>>>(bufB, n * 16, bn_ss2);

    // Layer 3 (reordered): gemm (no bias) -> bufA[N x 64] ; agg D=64 + bias -> d_out
    gemm_mfma_kernel<128, 64, false><<<gemm_grid, 256, 0, stream>>>(bufB, Whi3, Wlo3, nullptr, bufA, n);
    agg_vec_kernel<64, false, true, true><<<agg_grid, 256, 0, stream>>>(
        bufA, row_ptr, col_sorted, nullptr, b3f, d_out, flags, n);
}